// Round 22
// baseline (36.845 us; speedup 1.0000x reference)
//
#include <hip/hip_runtime.h>
#include <math.h>

#define B_ 8
#define N_ 128
#define M_ 256
#define F_ 256

#define LOG2E2 2.8853900817779268f  // 2*log2(e)

// ---------------------------------------------------------------------------
// K1-lite (r13, unchanged): u[r][g] = (x[r,:].Uw[g,:] + Ub[g]) * 2log2e.
// ---------------------------------------------------------------------------
__global__ __launch_bounds__(256) void k1_lite(const float* __restrict__ x,
                                               const float* __restrict__ Uw,
                                               const float* __restrict__ Ub,
                                               float* __restrict__ u) {
  const int g  = threadIdx.x;
  const int r0 = blockIdx.x * 4;
  const float* __restrict__ uwr = Uw + (size_t)g * F_;
  const float* __restrict__ xr  = x + (size_t)r0 * F_;

  float a0 = 0.f, a1 = 0.f, a2 = 0.f, a3 = 0.f;
#pragma unroll 4
  for (int f = 0; f < F_; f += 4) {
    const float4 wv = *(const float4*)&uwr[f];
    const float4 x0 = *(const float4*)&xr[0 * F_ + f];
    const float4 x1 = *(const float4*)&xr[1 * F_ + f];
    const float4 x2 = *(const float4*)&xr[2 * F_ + f];
    const float4 x3 = *(const float4*)&xr[3 * F_ + f];
    a0 = fmaf(wv.x, x0.x, a0); a0 = fmaf(wv.y, x0.y, a0);
    a0 = fmaf(wv.z, x0.z, a0); a0 = fmaf(wv.w, x0.w, a0);
    a1 = fmaf(wv.x, x1.x, a1); a1 = fmaf(wv.y, x1.y, a1);
    a1 = fmaf(wv.z, x1.z, a1); a1 = fmaf(wv.w, x1.w, a1);
    a2 = fmaf(wv.x, x2.x, a2); a2 = fmaf(wv.y, x2.y, a2);
    a2 = fmaf(wv.z, x2.z, a2); a2 = fmaf(wv.w, x2.w, a2);
    a3 = fmaf(wv.x, x3.x, a3); a3 = fmaf(wv.y, x3.y, a3);
    a3 = fmaf(wv.z, x3.z, a3); a3 = fmaf(wv.w, x3.w, a3);
  }
  const float ubv = Ub[g];
  u[(size_t)(r0 + 0) * F_ + g] = (a0 + ubv) * LOG2E2;
  u[(size_t)(r0 + 1) * F_ + g] = (a1 + ubv) * LOG2E2;
  u[(size_t)(r0 + 2) * F_ + g] = (a2 + ubv) * LOG2E2;
  u[(size_t)(r0 + 3) * F_ + g] = (a3 + ubv) * LOG2E2;
}

// ---------------------------------------------------------------------------
// K2 v15 = r18's kernel + two register-residency tools:
//  (1) amdgpu_waves_per_eu(1,4): bounds occupancy to the 4 waves/EU we launch
//      -> register budget 128 (vs the heuristic's 32 that caused operand
//      refetch + serialized ~60cy/QUAD dependency chains; r20 PMC: VGPR=32,
//      VALUBusy 49%).
//  (2) asm-pin yv after staging: values become opaque asm outputs -> the
//      compiler CANNOT rematerialize/refetch the y loads; the 32 VGPRs must
//      stay live, enabling cross-QUAD software pipelining.
// Hot loop math (EXACT paired reciprocal):
//   w0/d0 + w1/d1 = (w0*d1 + w1*d0) * rcp(d0*d1),  d = 1 + 2^t
// S[n][m] = sum_f Ww[f]/(1+2^(us[n][f]*y[m][f])); alpha = Wsum - 2S
// monotone-decreasing => MIN-reduce S (Wsum, W_b cancel in max/softmax).
// Grid (mg 0..3, ns 0..15, b 0..7) = 512 blocks, 512 threads (8 waves).
// Partials: rminp[b][mg][n] (min over 64 m), cminp[b][ns][m] (min over 8 n).
// ---------------------------------------------------------------------------
__global__ __launch_bounds__(512)
__attribute__((amdgpu_waves_per_eu(1, 4)))
void k2_alpha(const float* __restrict__ u, const float* __restrict__ y,
              const float* __restrict__ Ww,
              float* __restrict__ rminp, float* __restrict__ cminp) {
  __shared__ float us[8][F_];        //  8 KB
  __shared__ float red[8][8][64];    // 16 KB  [n][fc][m-lane]
  __shared__ float sm[8][64];        //  2 KB

  const int tid  = threadIdx.x;
  const int mg   = blockIdx.x;   // 0..3
  const int ns   = blockIdx.y;   // 0..15
  const int b    = blockIdx.z;   // 0..7
  const int n0   = ns * 8;
  const int m0   = mg * 64;
  const int lane = tid & 63;
  const int w    = tid >> 6;
  const int fc   = __builtin_amdgcn_readfirstlane(w);   // 0..7 (32 f each)

  // ---- stage this block's 8 u rows into LDS (coalesced, once) ----
  {
    const int r = tid >> 6, c = (tid & 63) * 4;
    *(float4*)&us[r][c] =
        *(const float4*)&u[(size_t)(b * N_ + n0 + r) * F_ + c];
  }

  // ---- per-thread y chunk (32 VGPR, asm-pinned) + wave-uniform Ww ----
  float4 yv[8];
  float4 wwv[8];
  {
    const float* yr = y + ((size_t)(b * M_ + m0 + lane)) * F_ + fc * 32;
    const float* wr = Ww + fc * 32;
#pragma unroll
    for (int j = 0; j < 8; ++j) {
      yv[j]  = *(const float4*)&yr[4 * j];
      wwv[j] = *(const float4*)&wr[4 * j];
    }
  }
#pragma unroll
  for (int j = 0; j < 8; ++j) {
    asm volatile("" : "+v"(yv[j].x), "+v"(yv[j].y),
                      "+v"(yv[j].z), "+v"(yv[j].w));
  }
  __syncthreads();

  // ---- hot loop: paired-reciprocal terms (EXACT math) ----
#define QUAD(nn, j, S0, S1)                                                   \
  do {                                                                        \
    const float4 uv = *(const float4*)&us[nn][fc * 32 + 4 * (j)];             \
    const float t0 = uv.x * yv[j].x;                                          \
    const float t1 = uv.y * yv[j].y;                                          \
    const float t2 = uv.z * yv[j].z;                                          \
    const float t3 = uv.w * yv[j].w;                                          \
    const float d0 = 1.f + __builtin_amdgcn_exp2f(t0);                        \
    const float d1 = 1.f + __builtin_amdgcn_exp2f(t1);                        \
    const float d2 = 1.f + __builtin_amdgcn_exp2f(t2);                        \
    const float d3 = 1.f + __builtin_amdgcn_exp2f(t3);                        \
    const float n01 = fmaf(wwv[j].x, d1, wwv[j].y * d0);                      \
    const float n23 = fmaf(wwv[j].z, d3, wwv[j].w * d2);                      \
    S0 = fmaf(n01, __builtin_amdgcn_rcpf(d0 * d1), S0);                       \
    S1 = fmaf(n23, __builtin_amdgcn_rcpf(d2 * d3), S1);                       \
  } while (0)

#define DO_N(nn, A)                                                                      \
  do {                                                                                   \
    float s0 = 0.f, s1 = 0.f;                                                            \
    QUAD(nn, 0, s0, s1); QUAD(nn, 1, s0, s1); QUAD(nn, 2, s0, s1); QUAD(nn, 3, s0, s1);  \
    QUAD(nn, 4, s0, s1); QUAD(nn, 5, s0, s1); QUAD(nn, 6, s0, s1); QUAD(nn, 7, s0, s1);  \
    A = s0 + s1;                                                                         \
  } while (0)

  float a0, a1, a2, a3, a4, a5, a6, a7;
  DO_N(0, a0); DO_N(1, a1); DO_N(2, a2); DO_N(3, a3);
  DO_N(4, a4); DO_N(5, a5); DO_N(6, a6); DO_N(7, a7);
#undef DO_N
#undef QUAD

  // ---- cross-fc sum ----
  red[0][fc][lane] = a0; red[1][fc][lane] = a1;
  red[2][fc][lane] = a2; red[3][fc][lane] = a3;
  red[4][fc][lane] = a4; red[5][fc][lane] = a5;
  red[6][fc][lane] = a6; red[7][fc][lane] = a7;
  __syncthreads();

  float S = 0.f;
#pragma unroll
  for (int k = 0; k < 8; ++k) S += red[w][k][lane];

  // row-min partial (over this block's 64 m)
  float r = S;
#pragma unroll
  for (int s = 32; s; s >>= 1) r = fminf(r, __shfl_xor(r, s));
  if (lane == 0) rminp[((size_t)b * 4 + mg) * N_ + n0 + w] = r;

  // col-min partial (over this block's 8 n)
  sm[w][lane] = S;
  __syncthreads();
  if (w == 0) {
    float c = sm[0][lane];
#pragma unroll
    for (int k = 1; k < 8; ++k) c = fminf(c, sm[k][lane]);
    cminp[((size_t)b * 16 + ns) * M_ + m0 + lane] = c;
  }
}

// ---------------------------------------------------------------------------
// KB (r14/r18, unchanged): 64 blocks (b x task x f-quarter), 256 threads.
// Softmax inputs are -2 * min-partials (exact, shift-invariant).
// ---------------------------------------------------------------------------
__global__ __launch_bounds__(256) void kb_final(
    const float* __restrict__ x, const float* __restrict__ y,
    const float* __restrict__ rminp, const float* __restrict__ cminp,
    float* __restrict__ out) {
  const int b    = blockIdx.x;
  const int task = blockIdx.y;
  const int fq   = blockIdx.z;
  const int tid  = threadIdx.x;
  const int w    = tid >> 6;
  __shared__ float wgt[M_];
  __shared__ float redv[4];
  __shared__ float part[4][64];

  if (task == 0) {
    float rv = -INFINITY;
    if (tid < N_) {
      float v = INFINITY;
#pragma unroll
      for (int mg = 0; mg < 4; ++mg)
        v = fminf(v, rminp[((size_t)b * 4 + mg) * N_ + tid]);
      rv = -2.f * v;
    }
    float m1 = rv;
#pragma unroll
    for (int s = 32; s; s >>= 1) m1 = fmaxf(m1, __shfl_xor(m1, s));
    if ((tid & 63) == 0) redv[w] = m1;
    __syncthreads();
    m1 = fmaxf(fmaxf(redv[0], redv[1]), fmaxf(redv[2], redv[3]));
    __syncthreads();
    const float e1 = (tid < N_) ? __expf(rv - m1) : 0.f;
    float s1 = e1;
#pragma unroll
    for (int s = 32; s; s >>= 1) s1 += __shfl_xor(s1, s);
    if ((tid & 63) == 0) redv[w] = s1;
    __syncthreads();
    s1 = redv[0] + redv[1] + redv[2] + redv[3];
    if (tid < N_) wgt[tid] = e1 / s1;
    __syncthreads();

    const int f = fq * 64 + (tid & 63);
    float acc = 0.f;
#pragma unroll 8
    for (int n = w; n < N_; n += 4)
      acc = fmaf(wgt[n], x[(size_t)(b * N_ + n) * F_ + f], acc);
    part[w][tid & 63] = acc;
    __syncthreads();
    if (tid < 64)
      out[b * (2 * F_) + fq * 64 + tid] =
          part[0][tid] + part[1][tid] + part[2][tid] + part[3][tid];
  } else {
    float cv;
    {
      float c = INFINITY;
#pragma unroll
      for (int ns = 0; ns < 16; ++ns)
        c = fminf(c, cminp[((size_t)b * 16 + ns) * M_ + tid]);
      cv = -2.f * c;
    }
    float m2 = cv;
#pragma unroll
    for (int s = 32; s; s >>= 1) m2 = fmaxf(m2, __shfl_xor(m2, s));
    if ((tid & 63) == 0) redv[w] = m2;
    __syncthreads();
    m2 = fmaxf(fmaxf(redv[0], redv[1]), fmaxf(redv[2], redv[3]));
    __syncthreads();
    const float e2 = __expf(cv - m2);
    float s2 = e2;
#pragma unroll
    for (int s = 32; s; s >>= 1) s2 += __shfl_xor(s2, s);
    if ((tid & 63) == 0) redv[w] = s2;
    __syncthreads();
    s2 = redv[0] + redv[1] + redv[2] + redv[3];
    wgt[tid] = e2 / s2;
    __syncthreads();

    const int f = fq * 64 + (tid & 63);
    float acc = 0.f;
#pragma unroll 8
    for (int m = w; m < M_; m += 4)
      acc = fmaf(wgt[m], y[(size_t)(b * M_ + m) * F_ + f], acc);
    part[w][tid & 63] = acc;
    __syncthreads();
    if (tid < 64)
      out[b * (2 * F_) + F_ + fq * 64 + tid] =
          part[0][tid] + part[1][tid] + part[2][tid] + part[3][tid];
  }
}

// ---------------------------------------------------------------------------
extern "C" void kernel_launch(void* const* d_in, const int* in_sizes, int n_in,
                              void* d_out, int out_size, void* d_ws, size_t ws_size,
                              hipStream_t stream) {
  (void)in_sizes; (void)n_in; (void)out_size; (void)ws_size;
  const float* x  = (const float*)d_in[0];
  const float* y  = (const float*)d_in[1];
  const float* Uw = (const float*)d_in[2];
  const float* Ub = (const float*)d_in[3];
  const float* Ww = (const float*)d_in[4];
  // d_in[5] (W_b) unused: max/softmax pipeline is shift-invariant.

  float* u     = (float*)d_ws;                 // [B][N][F]    262144 f
  float* rminp = u + B_ * N_ * F_;             // [B][4][N]      4096 f
  float* cminp = rminp + B_ * 4 * N_;          // [B][16][M]   32768 f
  float* outp  = (float*)d_out;

  k1_lite<<<dim3((B_ * N_) / 4), 256, 0, stream>>>(x, Uw, Ub, u);
  k2_alpha<<<dim3(4, 16, B_), 512, 0, stream>>>(u, y, Ww, rminp, cminp);
  kb_final<<<dim3(B_, 2, 4), 256, 0, stream>>>(x, y, rminp, cminp, outp);
}

// Round 23
// 34.980 us; speedup vs baseline: 1.0533x; 1.0533x over previous
//
#include <hip/hip_runtime.h>
#include <math.h>

#define B_ 8
#define N_ 128
#define M_ 256
#define F_ 256

#define LOG2E2 2.8853900817779268f  // 2*log2(e)

// ---------------------------------------------------------------------------
// K1-lite (r13): u[r][g] = (x[r,:].Uw[g,:] + Ub[g]) * 2log2e.
// No LDS; lane = output column g; 4 rows/block; x rows via scalar cache.
// ---------------------------------------------------------------------------
__global__ __launch_bounds__(256) void k1_lite(const float* __restrict__ x,
                                               const float* __restrict__ Uw,
                                               const float* __restrict__ Ub,
                                               float* __restrict__ u) {
  const int g  = threadIdx.x;
  const int r0 = blockIdx.x * 4;
  const float* __restrict__ uwr = Uw + (size_t)g * F_;
  const float* __restrict__ xr  = x + (size_t)r0 * F_;

  float a0 = 0.f, a1 = 0.f, a2 = 0.f, a3 = 0.f;
#pragma unroll 4
  for (int f = 0; f < F_; f += 4) {
    const float4 wv = *(const float4*)&uwr[f];
    const float4 x0 = *(const float4*)&xr[0 * F_ + f];
    const float4 x1 = *(const float4*)&xr[1 * F_ + f];
    const float4 x2 = *(const float4*)&xr[2 * F_ + f];
    const float4 x3 = *(const float4*)&xr[3 * F_ + f];
    a0 = fmaf(wv.x, x0.x, a0); a0 = fmaf(wv.y, x0.y, a0);
    a0 = fmaf(wv.z, x0.z, a0); a0 = fmaf(wv.w, x0.w, a0);
    a1 = fmaf(wv.x, x1.x, a1); a1 = fmaf(wv.y, x1.y, a1);
    a1 = fmaf(wv.z, x1.z, a1); a1 = fmaf(wv.w, x1.w, a1);
    a2 = fmaf(wv.x, x2.x, a2); a2 = fmaf(wv.y, x2.y, a2);
    a2 = fmaf(wv.z, x2.z, a2); a2 = fmaf(wv.w, x2.w, a2);
    a3 = fmaf(wv.x, x3.x, a3); a3 = fmaf(wv.y, x3.y, a3);
    a3 = fmaf(wv.z, x3.z, a3); a3 = fmaf(wv.w, x3.w, a3);
  }
  const float ubv = Ub[g];
  u[(size_t)(r0 + 0) * F_ + g] = (a0 + ubv) * LOG2E2;
  u[(size_t)(r0 + 1) * F_ + g] = (a1 + ubv) * LOG2E2;
  u[(size_t)(r0 + 2) * F_ + g] = (a2 + ubv) * LOG2E2;
  u[(size_t)(r0 + 3) * F_ + g] = (a3 + ubv) * LOG2E2;
}

// ---------------------------------------------------------------------------
// K2 (r18 best, 35.11 us total): paired-reciprocal hot loop (EXACT math):
//   w0/d0 + w1/d1 = (w0*d1 + w1*d0) * rcp(d0*d1),  d = 1 + 2^t
// S[n][m] = sum_f Ww[f]/(1+2^(us[n][f]*y[m][f])); alpha = Wsum - 2S
// monotone-decreasing => MIN-reduce S (Wsum, W_b cancel in max/softmax).
// Grid (mg 0..3, ns 0..15, b 0..7) = 512 blocks, 512 threads (8 waves).
// NO __launch_bounds__/attributes: every steering variant tried (r8-r22:
// (512),(512,1),(512,2),(512,4),waves_per_eu(1,4),asm-pin) was equal or
// worse; the backend pins this shape at 32-64 VGPR regardless.
// Partials: rminp[b][mg][n] (min over 64 m), cminp[b][ns][m] (min over 8 n).
// ---------------------------------------------------------------------------
__global__ void k2_alpha(const float* __restrict__ u,
                         const float* __restrict__ y,
                         const float* __restrict__ Ww,
                         float* __restrict__ rminp,
                         float* __restrict__ cminp) {
  __shared__ float us[8][F_];        //  8 KB
  __shared__ float red[8][8][64];    // 16 KB  [n][fc][m-lane]
  __shared__ float sm[8][64];        //  2 KB

  const int tid  = threadIdx.x;
  const int mg   = blockIdx.x;   // 0..3
  const int ns   = blockIdx.y;   // 0..15
  const int b    = blockIdx.z;   // 0..7
  const int n0   = ns * 8;
  const int m0   = mg * 64;
  const int lane = tid & 63;
  const int w    = tid >> 6;
  const int fc   = __builtin_amdgcn_readfirstlane(w);   // 0..7 (32 f each)

  // ---- stage this block's 8 u rows into LDS (coalesced, once) ----
  {
    const int r = tid >> 6, c = (tid & 63) * 4;
    *(float4*)&us[r][c] =
        *(const float4*)&u[(size_t)(b * N_ + n0 + r) * F_ + c];
  }

  // ---- per-thread y chunk + wave-uniform Ww chunk ----
  float4 yv[8];
  float4 wwv[8];
  {
    const float* yr = y + ((size_t)(b * M_ + m0 + lane)) * F_ + fc * 32;
    const float* wr = Ww + fc * 32;
#pragma unroll
    for (int j = 0; j < 8; ++j) {
      yv[j]  = *(const float4*)&yr[4 * j];
      wwv[j] = *(const float4*)&wr[4 * j];
    }
  }
  __syncthreads();

  // ---- hot loop: paired-reciprocal terms (EXACT math) ----
#define QUAD(nn, j, S0, S1)                                                   \
  do {                                                                        \
    const float4 uv = *(const float4*)&us[nn][fc * 32 + 4 * (j)];             \
    const float t0 = uv.x * yv[j].x;                                          \
    const float t1 = uv.y * yv[j].y;                                          \
    const float t2 = uv.z * yv[j].z;                                          \
    const float t3 = uv.w * yv[j].w;                                          \
    const float d0 = 1.f + __builtin_amdgcn_exp2f(t0);                        \
    const float d1 = 1.f + __builtin_amdgcn_exp2f(t1);                        \
    const float d2 = 1.f + __builtin_amdgcn_exp2f(t2);                        \
    const float d3 = 1.f + __builtin_amdgcn_exp2f(t3);                        \
    const float n01 = fmaf(wwv[j].x, d1, wwv[j].y * d0);                      \
    const float n23 = fmaf(wwv[j].z, d3, wwv[j].w * d2);                      \
    S0 = fmaf(n01, __builtin_amdgcn_rcpf(d0 * d1), S0);                       \
    S1 = fmaf(n23, __builtin_amdgcn_rcpf(d2 * d3), S1);                       \
  } while (0)

#define DO_N(nn, A)                                                                      \
  do {                                                                                   \
    float s0 = 0.f, s1 = 0.f;                                                            \
    QUAD(nn, 0, s0, s1); QUAD(nn, 1, s0, s1); QUAD(nn, 2, s0, s1); QUAD(nn, 3, s0, s1);  \
    QUAD(nn, 4, s0, s1); QUAD(nn, 5, s0, s1); QUAD(nn, 6, s0, s1); QUAD(nn, 7, s0, s1);  \
    A = s0 + s1;                                                                         \
  } while (0)

  float a0, a1, a2, a3, a4, a5, a6, a7;
  DO_N(0, a0); DO_N(1, a1); DO_N(2, a2); DO_N(3, a3);
  DO_N(4, a4); DO_N(5, a5); DO_N(6, a6); DO_N(7, a7);
#undef DO_N
#undef QUAD

  // ---- cross-fc sum ----
  red[0][fc][lane] = a0; red[1][fc][lane] = a1;
  red[2][fc][lane] = a2; red[3][fc][lane] = a3;
  red[4][fc][lane] = a4; red[5][fc][lane] = a5;
  red[6][fc][lane] = a6; red[7][fc][lane] = a7;
  __syncthreads();

  float S = 0.f;
#pragma unroll
  for (int k = 0; k < 8; ++k) S += red[w][k][lane];

  // row-min partial (over this block's 64 m)
  float r = S;
#pragma unroll
  for (int s = 32; s; s >>= 1) r = fminf(r, __shfl_xor(r, s));
  if (lane == 0) rminp[((size_t)b * 4 + mg) * N_ + n0 + w] = r;

  // col-min partial (over this block's 8 n)
  sm[w][lane] = S;
  __syncthreads();
  if (w == 0) {
    float c = sm[0][lane];
#pragma unroll
    for (int k = 1; k < 8; ++k) c = fminf(c, sm[k][lane]);
    cminp[((size_t)b * 16 + ns) * M_ + m0 + lane] = c;
  }
}

// ---------------------------------------------------------------------------
// KB (r14/r18): 64 blocks (b x task x f-quarter), 256 threads.
// Softmax inputs are -2 * min-partials (exact, shift-invariant).
// ---------------------------------------------------------------------------
__global__ __launch_bounds__(256) void kb_final(
    const float* __restrict__ x, const float* __restrict__ y,
    const float* __restrict__ rminp, const float* __restrict__ cminp,
    float* __restrict__ out) {
  const int b    = blockIdx.x;
  const int task = blockIdx.y;
  const int fq   = blockIdx.z;
  const int tid  = threadIdx.x;
  const int w    = tid >> 6;
  __shared__ float wgt[M_];
  __shared__ float redv[4];
  __shared__ float part[4][64];

  if (task == 0) {
    float rv = -INFINITY;
    if (tid < N_) {
      float v = INFINITY;
#pragma unroll
      for (int mg = 0; mg < 4; ++mg)
        v = fminf(v, rminp[((size_t)b * 4 + mg) * N_ + tid]);
      rv = -2.f * v;
    }
    float m1 = rv;
#pragma unroll
    for (int s = 32; s; s >>= 1) m1 = fmaxf(m1, __shfl_xor(m1, s));
    if ((tid & 63) == 0) redv[w] = m1;
    __syncthreads();
    m1 = fmaxf(fmaxf(redv[0], redv[1]), fmaxf(redv[2], redv[3]));
    __syncthreads();
    const float e1 = (tid < N_) ? __expf(rv - m1) : 0.f;
    float s1 = e1;
#pragma unroll
    for (int s = 32; s; s >>= 1) s1 += __shfl_xor(s1, s);
    if ((tid & 63) == 0) redv[w] = s1;
    __syncthreads();
    s1 = redv[0] + redv[1] + redv[2] + redv[3];
    if (tid < N_) wgt[tid] = e1 / s1;
    __syncthreads();

    const int f = fq * 64 + (tid & 63);
    float acc = 0.f;
#pragma unroll 8
    for (int n = w; n < N_; n += 4)
      acc = fmaf(wgt[n], x[(size_t)(b * N_ + n) * F_ + f], acc);
    part[w][tid & 63] = acc;
    __syncthreads();
    if (tid < 64)
      out[b * (2 * F_) + fq * 64 + tid] =
          part[0][tid] + part[1][tid] + part[2][tid] + part[3][tid];
  } else {
    float cv;
    {
      float c = INFINITY;
#pragma unroll
      for (int ns = 0; ns < 16; ++ns)
        c = fminf(c, cminp[((size_t)b * 16 + ns) * M_ + tid]);
      cv = -2.f * c;
    }
    float m2 = cv;
#pragma unroll
    for (int s = 32; s; s >>= 1) m2 = fmaxf(m2, __shfl_xor(m2, s));
    if ((tid & 63) == 0) redv[w] = m2;
    __syncthreads();
    m2 = fmaxf(fmaxf(redv[0], redv[1]), fmaxf(redv[2], redv[3]));
    __syncthreads();
    const float e2 = __expf(cv - m2);
    float s2 = e2;
#pragma unroll
    for (int s = 32; s; s >>= 1) s2 += __shfl_xor(s2, s);
    if ((tid & 63) == 0) redv[w] = s2;
    __syncthreads();
    s2 = redv[0] + redv[1] + redv[2] + redv[3];
    wgt[tid] = e2 / s2;
    __syncthreads();

    const int f = fq * 64 + (tid & 63);
    float acc = 0.f;
#pragma unroll 8
    for (int m = w; m < M_; m += 4)
      acc = fmaf(wgt[m], y[(size_t)(b * M_ + m) * F_ + f], acc);
    part[w][tid & 63] = acc;
    __syncthreads();
    if (tid < 64)
      out[b * (2 * F_) + F_ + fq * 64 + tid] =
          part[0][tid] + part[1][tid] + part[2][tid] + part[3][tid];
  }
}

// ---------------------------------------------------------------------------
extern "C" void kernel_launch(void* const* d_in, const int* in_sizes, int n_in,
                              void* d_out, int out_size, void* d_ws, size_t ws_size,
                              hipStream_t stream) {
  (void)in_sizes; (void)n_in; (void)out_size; (void)ws_size;
  const float* x  = (const float*)d_in[0];
  const float* y  = (const float*)d_in[1];
  const float* Uw = (const float*)d_in[2];
  const float* Ub = (const float*)d_in[3];
  const float* Ww = (const float*)d_in[4];
  // d_in[5] (W_b) unused: max/softmax pipeline is shift-invariant.

  float* u     = (float*)d_ws;                 // [B][N][F]    262144 f
  float* rminp = u + B_ * N_ * F_;             // [B][4][N]      4096 f
  float* cminp = rminp + B_ * 4 * N_;          // [B][16][M]   32768 f
  float* outp  = (float*)d_out;

  k1_lite<<<dim3((B_ * N_) / 4), 256, 0, stream>>>(x, Uw, Ub, u);
  k2_alpha<<<dim3(4, 16, B_), 512, 0, stream>>>(u, y, Ww, rminp, cminp);
  kb_final<<<dim3(B_, 2, 4), 256, 0, stream>>>(x, y, rminp, cminp, outp);
}